// Round 5
// baseline (214.706 us; speedup 1.0000x reference)
//
#include <hip/hip_runtime.h>

// 16-qubit variational-circuit simulator, B=128, re/im split into independent
// real states. Convention (proven): qubit q <-> global flat bit (15-q);
// out[b][i] = <Z_{15-i}> from |amp|^2 signs.
//
// st float layout (proven R3): addr = b<<16 | c<<15 | v(q14)<<14 | m(q0..3)<<10
//                                     | w(q10..13)<<6 | lane(q4..9)
//   m bit i <-> q(3-i); w bit i <-> q(13-i); lane bit i <-> q(9-i).
//
// P0 (512 blk x 1024 thr, 16 reals/thr) — EXACT R3-run proven implementation:
//   cone RY_k for q<=15-k, CZ_k pairs [0,14-k]; shfl_xor q4..q7, DPP q8/q9,
//   LDS exchange q10..13.
// P1 (512 blk x 512 thr, 64 reals/thr, NO LDS staging): regs idx=[q10..15]
//   (idx b5=q10..b0=q15), lane=[q4..9], Wp=[c,y1=q2,y0=q3], blk=b*4+GG (GG=[q0,q1]).
//   RY_k for q>=16-k; CZ_k pairs [15-k,14]; CZ_8 remainder dropped (diagonal,
//   last op before |a|^2). Only proven primitives (DPP, shfl, reg butterflies).

#define DEV __device__ __forceinline__
typedef unsigned long long ull;

DEV float2 cmul(float2 a, float2 b) {
    return make_float2(a.x * b.x - a.y * b.y, a.x * b.y + a.y * b.x);
}

DEV float dpp_xor1(float x) {
    return __int_as_float(__builtin_amdgcn_update_dpp(0, __float_as_int(x), 0xB1, 0xF, 0xF, false));
}
DEV float dpp_xor2(float x) {
    return __int_as_float(__builtin_amdgcn_update_dpp(0, __float_as_int(x), 0x4E, 0xF, 0xF, false));
}

// ---------------- precompute tables ----------------
__global__ void qsim_pre(const float* __restrict__ x, const float* __restrict__ theta,
                         float2* __restrict__ tsc, float4* __restrict__ psit) {
    const int t = blockIdx.x * 256 + threadIdx.x;
    if (t < 128) {
        float S, C; sincosf(0.5f * theta[t], &S, &C);
        tsc[t] = make_float2(C, S);
    }
    if (t < 2048) {
        const int b = t >> 4, q = t & 15;
        float sa, ca, SA, CA;
        sincosf(0.5f * x[b * 16 + q], &sa, &ca);
        sincosf(0.5f * theta[q], &SA, &CA);
        psit[t] = make_float4(CA * ca, SA * sa, SA * ca, -CA * sa);
    }
}

// ---------------- P0 (R3-run proven) ----------------
__global__ __launch_bounds__(1024, 8) void qsim_p0(const float4* __restrict__ psit,
                                                   const float2* __restrict__ tsc,
                                                   float* __restrict__ st) {
    const int bx = blockIdx.x;
    const int b = bx >> 2, v = (bx >> 1) & 1, c = bx & 1;
    const int tid = threadIdx.x;
    const int lane = tid & 63, w = tid >> 6;

    __shared__ float X[8][1024];  // 32 KB exchange

    // ---- product init through RY1 ----
    const float4* pb = psit + b * 16;
    float2 common = make_float2(1.f, 0.f);
#pragma unroll
    for (int q = 4; q <= 9; ++q) {
        float4 p = pb[q];
        int bit = (lane >> (9 - q)) & 1;
        common = cmul(common, bit ? make_float2(p.z, p.w) : make_float2(p.x, p.y));
    }
#pragma unroll
    for (int q = 10; q <= 13; ++q) {
        float4 p = pb[q];
        int bit = (w >> (13 - q)) & 1;
        common = cmul(common, bit ? make_float2(p.z, p.w) : make_float2(p.x, p.y));
    }
    {
        float4 p = pb[14];
        common = cmul(common, v ? make_float2(p.z, p.w) : make_float2(p.x, p.y));
    }
    float2 ps0[4], ps1[4];
#pragma unroll
    for (int q = 0; q < 4; ++q) {
        float4 p = pb[q];
        ps0[q] = make_float2(p.x, p.y);
        ps1[q] = make_float2(p.z, p.w);
    }

    float a[16];
#pragma unroll
    for (int m = 0; m < 16; ++m) {
        float2 prod = common;
#pragma unroll
        for (int q = 0; q < 4; ++q) {
            int bit = (m >> (3 - q)) & 1;
            prod = cmul(prod, bit ? ps1[q] : ps0[q]);
        }
        a[m] = c ? prod.y : prod.x;
    }

    // ---- CZ sign machinery (proven) ----
    unsigned Pm = 0;
    const int l5 = (lane >> 5) & 1;  // q4
#pragma unroll
    for (int m = 0; m < 16; ++m) {
        int m0 = m & 1, m1 = (m >> 1) & 1, m2 = (m >> 2) & 1, m3 = (m >> 3) & 1;
        int pm = ((m3 & m2) ^ (m2 & m1) ^ (m1 & m0) ^ (m0 & l5)) & 1;
        Pm |= ((unsigned)pm) << m;
    }
    const unsigned A = ((unsigned)lane << 5) | ((unsigned)w << 1) | (unsigned)v;
    const unsigned AA = (A & (A >> 1)) & 0x3FFu;

    auto czP0 = [&](int k) {
        unsigned T = __popc(AA >> (k - 1)) & 1u;
        unsigned Wm = T ? (Pm ^ 0xFFFFu) : Pm;
#pragma unroll
        for (int m = 0; m < 16; ++m) {
            unsigned sg = ((Wm >> m) & 1u) << 31;
            a[m] = __uint_as_float(__float_as_uint(a[m]) ^ sg);
        }
    };

    czP0(1);

    for (int k = 2; k <= 8; ++k) {
        // reg gates q=0..3 (always in cone)
#pragma unroll
        for (int q = 0; q < 4; ++q) {
            float2 cs = tsc[(k - 1) * 16 + q];
            const float C = cs.x, S = cs.y;
            const int mb = 1 << (3 - q);
#pragma unroll
            for (int m = 0; m < 16; ++m)
                if (!(m & mb)) {
                    float t0 = a[m], t1 = a[m | mb];
                    a[m]      = C * t0 - S * t1;
                    a[m | mb] = S * t0 + C * t1;
                }
        }
        // lane gates q=4..9: shfl_xor (q4..q7), DPP (q8,q9) — proven
#pragma unroll
        for (int q = 4; q <= 9; ++q) {
            if (q <= 15 - k) {
                float2 cs = tsc[(k - 1) * 16 + q];
                const float C = cs.x, S = cs.y;
                const int lb = 9 - q;
                const float Sg = ((lane >> lb) & 1) ? S : -S;
#pragma unroll
                for (int i = 0; i < 16; ++i) {
                    float p;
                    if (lb == 0)      p = dpp_xor1(a[i]);
                    else if (lb == 1) p = dpp_xor2(a[i]);
                    else              p = __shfl_xor(a[i], 1 << lb);
                    a[i] = C * a[i] + Sg * p;
                }
            }
        }
        // wave gates q=10..13 via LDS
#pragma unroll
        for (int q = 10; q <= 13; ++q) {
            if (q <= 15 - k) {
                float2 cs = tsc[(k - 1) * 16 + q];
                const float C = cs.x, S = cs.y;
                const int wb = 13 - q;
                const int pt = tid ^ (64 << wb);
                const float Sg = ((w >> wb) & 1) ? S : -S;
#pragma unroll
                for (int h = 0; h < 2; ++h) {
                    __syncthreads();
#pragma unroll
                    for (int i = 0; i < 8; ++i) X[i][tid] = a[h * 8 + i];
                    __syncthreads();
#pragma unroll
                    for (int i = 0; i < 8; ++i) {
                        float p = X[i][pt];
                        a[h * 8 + i] = C * a[h * 8 + i] + Sg * p;
                    }
                }
            }
        }
        czP0(k);
    }

    // coalesced store
    float* outp = st + (((size_t)(b * 2 + c)) << 15) + ((size_t)v << 14);
#pragma unroll
    for (int m = 0; m < 16; ++m) outp[(m << 10) | tid] = a[m];
}

// ---------------- P1 helpers ----------------
constexpr ull czc(int k) {
    // cumulative per-amp CZ mask over idx (6b): pairs t = bit t & bit t+1, t<min(k,5)
    ull m = 0;
    for (int i = 0; i < 64; ++i) {
        int p = 0;
        for (int t = 0; t < (k < 5 ? k : 5); ++t) p ^= ((i >> t) & 1) & ((i >> (t + 1)) & 1);
        m |= (ull)p << i;
    }
    return m;
}

template <int MQ>
DEV void rg64(float (&a)[64], float C, float S) {
#pragma unroll
    for (int i = 0; i < 64; ++i)
        if (!(i & MQ)) {
            float t0 = a[i], t1 = a[i | MQ];
            a[i]      = C * t0 - S * t1;
            a[i | MQ] = S * t0 + C * t1;
        }
}

template <int K>
DEV void czapply(float (&a)[64], unsigned shi, unsigned sall) {
    constexpr ull M = czc(K);
    const unsigned dlo = (K >= 7) ? sall : 0u;
    const unsigned dhi = (K >= 6) ? ((K >= 7) ? (sall ^ shi) : shi) : 0u;
#pragma unroll
    for (int i = 0; i < 64; ++i) {
        unsigned cb = (unsigned)(((M >> i) & 1ull) << 31);
        unsigned d = (i < 32) ? dlo : dhi;
        a[i] = __uint_as_float(__float_as_uint(a[i]) ^ cb ^ d);
    }
}

template <int K>
DEV void p1_layer(float (&a)[64], const float2* __restrict__ tsc,
                  int lane, unsigned shi, unsigned sall) {
    {  // q15 (mask 1), q14 (mask 2): always for K>=2
        float2 cs = tsc[(K - 1) * 16 + 15]; rg64<1>(a, cs.x, cs.y);
        cs = tsc[(K - 1) * 16 + 14];        rg64<2>(a, cs.x, cs.y);
    }
    if constexpr (K >= 3) { float2 cs = tsc[(K - 1) * 16 + 13]; rg64<4>(a, cs.x, cs.y); }
    if constexpr (K >= 4) { float2 cs = tsc[(K - 1) * 16 + 12]; rg64<8>(a, cs.x, cs.y); }
    if constexpr (K >= 5) { float2 cs = tsc[(K - 1) * 16 + 11]; rg64<16>(a, cs.x, cs.y); }
    if constexpr (K >= 6) { float2 cs = tsc[(K - 1) * 16 + 10]; rg64<32>(a, cs.x, cs.y); }
    if constexpr (K >= 7) {  // q9: lane xor1 (DPP)
        float2 cs = tsc[(K - 1) * 16 + 9];
        const float C = cs.x, S = cs.y;
        const float Sg = (lane & 1) ? S : -S;
#pragma unroll
        for (int i = 0; i < 64; ++i) { float p = dpp_xor1(a[i]); a[i] = C * a[i] + Sg * p; }
    }
    if constexpr (K == 8) {  // q8: lane xor2 (DPP)
        float2 cs = tsc[(K - 1) * 16 + 8];
        const float C = cs.x, S = cs.y;
        const float Sg = ((lane >> 1) & 1) ? S : -S;
#pragma unroll
        for (int i = 0; i < 64; ++i) { float p = dpp_xor2(a[i]); a[i] = C * a[i] + Sg * p; }
    }
    if constexpr (K < 8) czapply<K>(a, shi, sall);  // CZ_8 remainder: diagonal, dropped
}

// ---------------- P1 ----------------
__global__ __launch_bounds__(512, 4) void qsim_p1(const float4* __restrict__ psit,
                                                  const float2* __restrict__ tsc,
                                                  const float* __restrict__ st,
                                                  float* __restrict__ partials) {
    const int blk = blockIdx.x;           // 512 = b(128) x GG(q0,q1)
    const int b = blk >> 2, GG = blk & 3;
    const int tid = threadIdx.x;
    const int lane = tid & 63, Wp = tid >> 6;      // Wp = [c, y1=q2, y0=q3]
    const int c = (Wp >> 2) & 1, y1 = (Wp >> 1) & 1, y0 = Wp & 1;
    const int mm = (GG << 2) | (y1 << 1) | y0;     // m-field = [q0..3]

    __shared__ float red[8][13];

    // ---- direct coalesced loads + psi15 fold ----
    const float4 p15 = psit[b * 16 + 15];
    const float cB0 = c ? p15.y : -p15.y;   // pairs with p15.x
    const float cB1 = c ? p15.w : -p15.w;   // pairs with p15.z
    const float* pA = st + (((size_t)b) << 16) + ((size_t)c << 15);
    const float* pB = st + (((size_t)b) << 16) + ((size_t)(c ^ 1) << 15);

    float a[64];  // idx = w4(4b: q10..13) | vv(q14) | h(q15)
#pragma unroll
    for (int w4 = 0; w4 < 16; ++w4) {
#pragma unroll
        for (int vv = 0; vv < 2; ++vv) {
            const int off = (vv << 14) | (mm << 10) | (w4 << 6) | lane;
            const float rA = pA[off], rB = pB[off];
            a[(w4 << 2) | (vv << 1)]     = p15.x * rA + cB0 * rB;
            a[(w4 << 2) | (vv << 1) | 1] = p15.z * rA + cB1 * rB;
        }
    }

    const unsigned shi  = ((unsigned)(lane & 1)) << 31;                   // t5: q9, hi amps
    const unsigned sall = ((unsigned)((lane >> 1) & lane & 1)) << 31;     // t6: q8&q9

    czapply<1>(a, shi, sall);
    p1_layer<2>(a, tsc, lane, shi, sall);
    p1_layer<3>(a, tsc, lane, shi, sall);
    p1_layer<4>(a, tsc, lane, shi, sall);
    p1_layer<5>(a, tsc, lane, shi, sall);
    p1_layer<6>(a, tsc, lane, shi, sall);
    p1_layer<7>(a, tsc, lane, shi, sall);
    p1_layer<8>(a, tsc, lane, shi, sall);

    // ---- measurement ----
    float Ssum = 0.f, Sq[6] = {0.f, 0.f, 0.f, 0.f, 0.f, 0.f};
#pragma unroll
    for (int i = 0; i < 64; ++i) {
        float pm = a[i] * a[i];
        Ssum += pm;
        if (i & 32) Sq[0] += pm;  // q10
        if (i & 16) Sq[1] += pm;  // q11
        if (i & 8)  Sq[2] += pm;  // q12
        if (i & 4)  Sq[3] += pm;  // q13
        if (i & 2)  Sq[4] += pm;  // q14
        if (i & 1)  Sq[5] += pm;  // q15
    }
    // Walsh cascade over lane bits (P + 6 signed sums of Ssum)
    float P = Ssum, Bv[6];
#pragma unroll
    for (int d = 0; d < 6; ++d) {
        float t = __shfl_xor(P, 1 << d);
        Bv[d] = ((lane >> d) & 1) ? (t - P) : (P - t);
        P += t;
#pragma unroll
        for (int e = 0; e < 6; ++e)
            if (e < d) Bv[e] += __shfl_xor(Bv[e], 1 << d);
    }
#pragma unroll
    for (int j = 0; j < 6; ++j)
#pragma unroll
        for (int d = 0; d < 6; ++d) Sq[j] += __shfl_xor(Sq[j], 1 << d);

    if (lane == 0) {
        red[Wp][0] = P;
#pragma unroll
        for (int d = 0; d < 6; ++d) red[Wp][1 + d] = Bv[d];
#pragma unroll
        for (int j = 0; j < 6; ++j) red[Wp][7 + j] = Sq[j];
    }
    __syncthreads();
    if (tid < 16) {
        const int i = tid;  // out index; q = 15 - i
        float r = 0.f;
#pragma unroll
        for (int Wt = 0; Wt < 8; ++Wt) {
            const float Av = red[Wt][0];
            if (i < 6)        r += Av - 2.f * red[Wt][12 - i];   // q10..15 (reg bits)
            else if (i < 12)  r += red[Wt][1 + (i - 6)];         // q4..9 (lane Walsh)
            else if (i == 12) r += (Wt & 1) ? -Av : Av;          // q3 = y0
            else if (i == 13) r += ((Wt >> 1) & 1) ? -Av : Av;   // q2 = y1
            else              r += Av;                           // q0,q1 block-fixed
        }
        if (i == 14 && (GG & 1)) r = -r;        // q1 = GG b0
        if (i == 15 && ((GG >> 1) & 1)) r = -r; // q0 = GG b1
        partials[(blk << 4) + i] = r;
    }
}

// ---------------- P2 ----------------
__global__ void qsim_p2(const float* __restrict__ partials, float* __restrict__ out) {
    const int idx = blockIdx.x * 256 + threadIdx.x;  // 2048 outputs
    if (idx < 2048) {
        const int b = idx >> 4, i = idx & 15;
        float s = 0.f;
#pragma unroll
        for (int g = 0; g < 4; ++g) s += partials[(((b << 2) | g) << 4) + i];
        out[idx] = s;
    }
}

extern "C" void kernel_launch(void* const* d_in, const int* in_sizes, int n_in,
                              void* d_out, int out_size, void* d_ws, size_t ws_size,
                              hipStream_t stream) {
    const float* x = (const float*)d_in[0];       // [128,16]
    const float* theta = (const float*)d_in[1];   // [128]
    float* out = (float*)d_out;                   // [128,16]
    float* ws = (float*)d_ws;
    float* st = ws;                               // 8388608 floats = 32 MiB
    float* partials = ws + 8388608;               // 8192 floats used
    float2* tsc = (float2*)(ws + 8388608 + 131072);          // 128 float2
    float4* psit = (float4*)(ws + 8388608 + 131072 + 256);   // 2048 float4

    qsim_pre<<<8, 256, 0, stream>>>(x, theta, tsc, psit);
    qsim_p0<<<512, 1024, 0, stream>>>(psit, tsc, st);
    qsim_p1<<<512, 512, 0, stream>>>(psit, tsc, st, partials);
    qsim_p2<<<8, 256, 0, stream>>>(partials, out);
}

// Round 6
// 131.309 us; speedup vs baseline: 1.6351x; 1.6351x over previous
//
#include <hip/hip_runtime.h>

// 16-qubit variational-circuit simulator, B=128, re/im split into independent
// real states. Convention (proven): qubit q <-> global flat bit (15-q);
// out[b][i] = <Z_{15-i}> from |amp|^2 signs.
//
// st float layout (proven R3/R5): addr = b<<16 | c<<15 | v(q14)<<14 | m(q0..3)<<10
//                                        | w(q10..13)<<6 | lane6(q4..9)
//   m bit i <-> q(3-i); w bit i <-> q(13-i); lane6 bit i <-> q(9-i).
//   => addr bits: 15=c, 14=q14, 13..10=q0..q3, 9..6=q10,q11,q12,q13, 5..0=q4..q9.
//
// P0 (512 blk x 1024 thr, 16 reals/thr) — EXACT R5 proven implementation.
// P1 v2 (2048 blk x 512 thr, 16 reals/thr, NO LDS, NO spill):
//   blk = b(128) x J(16; addr bits 13..10, J b0=q3..b3=q0);
//   Wp(8 waves) = [c(b2), q4(b1), q5(b0)]; lane: lb0=q11,lb1=q10,lb2=q9,lb3=q8,
//   lb4=q7,lb5=q6 (q6,q7 passive); regs n: b0=q15(fold), b1=q14, b2=q13, b3=q12.
//   RY_k for q>=16-k: q15,q14 reg; q13 (K>=3), q12 (K>=4) reg; q11 (K>=5) dpp1;
//   q10 (K>=6) dpp2; q9 (K>=7) shfl4; q8 (K=8) shfl8.
//   CZ_k remainder pairs t=14-q in [0,k-1]: t0..t2 amp masks, t3 = lb0&n3,
//   t4..t6 thread-fixed; CZ_8 dropped (diagonal, last op before |a|^2).

#define DEV __device__ __forceinline__
typedef unsigned long long ull;

DEV float2 cmul(float2 a, float2 b) {
    return make_float2(a.x * b.x - a.y * b.y, a.x * b.y + a.y * b.x);
}

DEV float dpp_xor1(float x) {
    return __int_as_float(__builtin_amdgcn_update_dpp(0, __float_as_int(x), 0xB1, 0xF, 0xF, false));
}
DEV float dpp_xor2(float x) {
    return __int_as_float(__builtin_amdgcn_update_dpp(0, __float_as_int(x), 0x4E, 0xF, 0xF, false));
}

// ---------------- precompute tables ----------------
__global__ void qsim_pre(const float* __restrict__ x, const float* __restrict__ theta,
                         float2* __restrict__ tsc, float4* __restrict__ psit) {
    const int t = blockIdx.x * 256 + threadIdx.x;
    if (t < 128) {
        float S, C; sincosf(0.5f * theta[t], &S, &C);
        tsc[t] = make_float2(C, S);
    }
    if (t < 2048) {
        const int b = t >> 4, q = t & 15;
        float sa, ca, SA, CA;
        sincosf(0.5f * x[b * 16 + q], &sa, &ca);
        sincosf(0.5f * theta[q], &SA, &CA);
        psit[t] = make_float4(CA * ca, SA * sa, SA * ca, -CA * sa);
    }
}

// ---------------- P0 (R5 proven, unchanged) ----------------
__global__ __launch_bounds__(1024, 8) void qsim_p0(const float4* __restrict__ psit,
                                                   const float2* __restrict__ tsc,
                                                   float* __restrict__ st) {
    const int bx = blockIdx.x;
    const int b = bx >> 2, v = (bx >> 1) & 1, c = bx & 1;
    const int tid = threadIdx.x;
    const int lane = tid & 63, w = tid >> 6;

    __shared__ float X[8][1024];  // 32 KB exchange

    // ---- product init through RY1 ----
    const float4* pb = psit + b * 16;
    float2 common = make_float2(1.f, 0.f);
#pragma unroll
    for (int q = 4; q <= 9; ++q) {
        float4 p = pb[q];
        int bit = (lane >> (9 - q)) & 1;
        common = cmul(common, bit ? make_float2(p.z, p.w) : make_float2(p.x, p.y));
    }
#pragma unroll
    for (int q = 10; q <= 13; ++q) {
        float4 p = pb[q];
        int bit = (w >> (13 - q)) & 1;
        common = cmul(common, bit ? make_float2(p.z, p.w) : make_float2(p.x, p.y));
    }
    {
        float4 p = pb[14];
        common = cmul(common, v ? make_float2(p.z, p.w) : make_float2(p.x, p.y));
    }
    float2 ps0[4], ps1[4];
#pragma unroll
    for (int q = 0; q < 4; ++q) {
        float4 p = pb[q];
        ps0[q] = make_float2(p.x, p.y);
        ps1[q] = make_float2(p.z, p.w);
    }

    float a[16];
#pragma unroll
    for (int m = 0; m < 16; ++m) {
        float2 prod = common;
#pragma unroll
        for (int q = 0; q < 4; ++q) {
            int bit = (m >> (3 - q)) & 1;
            prod = cmul(prod, bit ? ps1[q] : ps0[q]);
        }
        a[m] = c ? prod.y : prod.x;
    }

    // ---- CZ sign machinery (proven) ----
    unsigned Pm = 0;
    const int l5 = (lane >> 5) & 1;  // q4
#pragma unroll
    for (int m = 0; m < 16; ++m) {
        int m0 = m & 1, m1 = (m >> 1) & 1, m2 = (m >> 2) & 1, m3 = (m >> 3) & 1;
        int pm = ((m3 & m2) ^ (m2 & m1) ^ (m1 & m0) ^ (m0 & l5)) & 1;
        Pm |= ((unsigned)pm) << m;
    }
    const unsigned A = ((unsigned)lane << 5) | ((unsigned)w << 1) | (unsigned)v;
    const unsigned AA = (A & (A >> 1)) & 0x3FFu;

    auto czP0 = [&](int k) {
        unsigned T = __popc(AA >> (k - 1)) & 1u;
        unsigned Wm = T ? (Pm ^ 0xFFFFu) : Pm;
#pragma unroll
        for (int m = 0; m < 16; ++m) {
            unsigned sg = ((Wm >> m) & 1u) << 31;
            a[m] = __uint_as_float(__float_as_uint(a[m]) ^ sg);
        }
    };

    czP0(1);

    for (int k = 2; k <= 8; ++k) {
        // reg gates q=0..3 (always in cone)
#pragma unroll
        for (int q = 0; q < 4; ++q) {
            float2 cs = tsc[(k - 1) * 16 + q];
            const float C = cs.x, S = cs.y;
            const int mb = 1 << (3 - q);
#pragma unroll
            for (int m = 0; m < 16; ++m)
                if (!(m & mb)) {
                    float t0 = a[m], t1 = a[m | mb];
                    a[m]      = C * t0 - S * t1;
                    a[m | mb] = S * t0 + C * t1;
                }
        }
        // lane gates q=4..9: shfl_xor (q4..q7), DPP (q8,q9) — proven
#pragma unroll
        for (int q = 4; q <= 9; ++q) {
            if (q <= 15 - k) {
                float2 cs = tsc[(k - 1) * 16 + q];
                const float C = cs.x, S = cs.y;
                const int lb = 9 - q;
                const float Sg = ((lane >> lb) & 1) ? S : -S;
#pragma unroll
                for (int i = 0; i < 16; ++i) {
                    float p;
                    if (lb == 0)      p = dpp_xor1(a[i]);
                    else if (lb == 1) p = dpp_xor2(a[i]);
                    else              p = __shfl_xor(a[i], 1 << lb);
                    a[i] = C * a[i] + Sg * p;
                }
            }
        }
        // wave gates q=10..13 via LDS
#pragma unroll
        for (int q = 10; q <= 13; ++q) {
            if (q <= 15 - k) {
                float2 cs = tsc[(k - 1) * 16 + q];
                const float C = cs.x, S = cs.y;
                const int wb = 13 - q;
                const int pt = tid ^ (64 << wb);
                const float Sg = ((w >> wb) & 1) ? S : -S;
#pragma unroll
                for (int h = 0; h < 2; ++h) {
                    __syncthreads();
#pragma unroll
                    for (int i = 0; i < 8; ++i) X[i][tid] = a[h * 8 + i];
                    __syncthreads();
#pragma unroll
                    for (int i = 0; i < 8; ++i) {
                        float p = X[i][pt];
                        a[h * 8 + i] = C * a[h * 8 + i] + Sg * p;
                    }
                }
            }
        }
        czP0(k);
    }

    // coalesced store
    float* outp = st + (((size_t)(b * 2 + c)) << 15) + ((size_t)v << 14);
#pragma unroll
    for (int m = 0; m < 16; ++m) outp[(m << 10) | tid] = a[m];
}

// ---------------- P1 helpers ----------------
template <int K>
constexpr unsigned czmask16() {
    // per-amp parity over n (b0=q15,b1=q14,b2=q13,b3=q12):
    // t0=(q14,q15)=n1&n0 (K>=1); t1=(q13,q14)=n2&n1 (K>=2); t2=(q12,q13)=n3&n2 (K>=3)
    unsigned m = 0;
    for (int n = 0; n < 16; ++n) {
        int n0 = n & 1, n1 = (n >> 1) & 1, n2 = (n >> 2) & 1, n3 = (n >> 3) & 1;
        int p = n1 & n0;
        if (K >= 2) p ^= n2 & n1;
        if (K >= 3) p ^= n3 & n2;
        m |= (unsigned)(p & 1) << n;
    }
    return m;
}

template <int K>
DEV void czp1(float (&a)[16], int lb0, int lb1, int lb2, int lb3) {
    unsigned W = czmask16<K>();
    if (K >= 4 && lb0) W ^= 0xFF00u;           // t3 = (q11,q12) = lb0 & n3
    int T = 0;
    if (K >= 5) T ^= (lb1 & lb0);              // t4 = (q10,q11)
    if (K >= 6) T ^= (lb2 & lb1);              // t5 = (q9,q10)
    if (K >= 7) T ^= (lb3 & lb2);              // t6 = (q8,q9)
    if (T) W ^= 0xFFFFu;
#pragma unroll
    for (int n = 0; n < 16; ++n) {
        unsigned sg = ((W >> n) & 1u) << 31;
        a[n] = __uint_as_float(__float_as_uint(a[n]) ^ sg);
    }
}

template <int MQ>
DEV void rg16(float (&a)[16], float C, float S) {
#pragma unroll
    for (int n = 0; n < 16; ++n)
        if (!(n & MQ)) {
            float t0 = a[n], t1 = a[n | MQ];
            a[n]      = C * t0 - S * t1;
            a[n | MQ] = S * t0 + C * t1;
        }
}

template <int K>
DEV void p1_layer(float (&a)[16], const float2* __restrict__ tsc, int lane) {
    float2 cs = tsc[(K - 1) * 16 + 15]; rg16<1>(a, cs.x, cs.y);   // q15
    cs = tsc[(K - 1) * 16 + 14];        rg16<2>(a, cs.x, cs.y);   // q14
    if constexpr (K >= 3) { cs = tsc[(K - 1) * 16 + 13]; rg16<4>(a, cs.x, cs.y); }
    if constexpr (K >= 4) { cs = tsc[(K - 1) * 16 + 12]; rg16<8>(a, cs.x, cs.y); }
    if constexpr (K >= 5) {  // q11: lane xor1 (DPP)
        cs = tsc[(K - 1) * 16 + 11];
        const float C = cs.x, Sg = (lane & 1) ? cs.y : -cs.y;
#pragma unroll
        for (int n = 0; n < 16; ++n) { float p = dpp_xor1(a[n]); a[n] = C * a[n] + Sg * p; }
    }
    if constexpr (K >= 6) {  // q10: lane xor2 (DPP)
        cs = tsc[(K - 1) * 16 + 10];
        const float C = cs.x, Sg = ((lane >> 1) & 1) ? cs.y : -cs.y;
#pragma unroll
        for (int n = 0; n < 16; ++n) { float p = dpp_xor2(a[n]); a[n] = C * a[n] + Sg * p; }
    }
    if constexpr (K >= 7) {  // q9: lane xor4 (shfl, proven)
        cs = tsc[(K - 1) * 16 + 9];
        const float C = cs.x, Sg = ((lane >> 2) & 1) ? cs.y : -cs.y;
#pragma unroll
        for (int n = 0; n < 16; ++n) { float p = __shfl_xor(a[n], 4); a[n] = C * a[n] + Sg * p; }
    }
    if constexpr (K >= 8) {  // q8: lane xor8 (shfl, proven)
        cs = tsc[(K - 1) * 16 + 8];
        const float C = cs.x, Sg = ((lane >> 3) & 1) ? cs.y : -cs.y;
#pragma unroll
        for (int n = 0; n < 16; ++n) { float p = __shfl_xor(a[n], 8); a[n] = C * a[n] + Sg * p; }
    }
    if constexpr (K < 8) {
        const int lb0 = lane & 1, lb1 = (lane >> 1) & 1, lb2 = (lane >> 2) & 1, lb3 = (lane >> 3) & 1;
        czp1<K>(a, lb0, lb1, lb2, lb3);
    }
}

// ---------------- P1 ----------------
__global__ __launch_bounds__(512, 4) void qsim_p1(const float4* __restrict__ psit,
                                                  const float2* __restrict__ tsc,
                                                  const float* __restrict__ st,
                                                  float* __restrict__ partials) {
    const int blk = blockIdx.x;                 // 2048 = b(128) x J(16)
    const int b = blk >> 4, J = blk & 15;
    const int tid = threadIdx.x;
    const int lane = tid & 63, Wp = tid >> 6;   // Wp = [c(b2), q4(b1), q5(b0)]
    const int c = (Wp >> 2) & 1, q4 = (Wp >> 1) & 1, q5 = Wp & 1;

    __shared__ float red[8][11];

    const float4 p15 = psit[b * 16 + 15];
    const float cB0 = c ? p15.y : -p15.y;
    const float cB1 = c ? p15.w : -p15.w;

    // addr bits: 9=q10(lb1), 8=q11(lb0), 3..0=q6,q7,q8,q9 (lane b5..b2)
    const int laneoff = (((lane >> 1) & 1) << 9) | ((lane & 1) << 8) | ((lane >> 2) & 15);
    const int fixoff = (J << 10) | (q4 << 5) | (q5 << 4) | laneoff;
    const float* pA = st + (((size_t)b) << 16) + ((size_t)c << 15) + fixoff;
    const float* pB = st + (((size_t)b) << 16) + ((size_t)(c ^ 1) << 15) + fixoff;

    float a[16];  // n: b0=q15, b1=q14, b2=q13, b3=q12
#pragma unroll
    for (int q12 = 0; q12 < 2; ++q12)
#pragma unroll
        for (int q13 = 0; q13 < 2; ++q13)
#pragma unroll
            for (int q14 = 0; q14 < 2; ++q14) {
                const int off = (q14 << 14) | (q12 << 7) | (q13 << 6);
                const float rA = pA[off], rB = pB[off];
                const int n = (q12 << 3) | (q13 << 2) | (q14 << 1);
                a[n]     = p15.x * rA + cB0 * rB;   // h = q15 = 0
                a[n | 1] = p15.z * rA + cB1 * rB;   // h = q15 = 1
            }

    {
        const int lb0 = lane & 1, lb1 = (lane >> 1) & 1, lb2 = (lane >> 2) & 1, lb3 = (lane >> 3) & 1;
        czp1<1>(a, lb0, lb1, lb2, lb3);
    }
    p1_layer<2>(a, tsc, lane);
    p1_layer<3>(a, tsc, lane);
    p1_layer<4>(a, tsc, lane);
    p1_layer<5>(a, tsc, lane);
    p1_layer<6>(a, tsc, lane);
    p1_layer<7>(a, tsc, lane);
    p1_layer<8>(a, tsc, lane);

    // ---- measurement ----
    float Ssum = 0.f, Sq[4] = {0.f, 0.f, 0.f, 0.f};  // Sq[j]: n bit j set (q15,q14,q13,q12)
#pragma unroll
    for (int n = 0; n < 16; ++n) {
        float pm = a[n] * a[n];
        Ssum += pm;
        if (n & 1) Sq[0] += pm;
        if (n & 2) Sq[1] += pm;
        if (n & 4) Sq[2] += pm;
        if (n & 8) Sq[3] += pm;
    }
    // Walsh cascade over lane bits (proven R5): P + Bv[d] (signed by lane bit d)
    float P = Ssum, Bv[6];
#pragma unroll
    for (int d = 0; d < 6; ++d) {
        float t = __shfl_xor(P, 1 << d);
        Bv[d] = ((lane >> d) & 1) ? (t - P) : (P - t);
        P += t;
#pragma unroll
        for (int e = 0; e < 6; ++e)
            if (e < d) Bv[e] += __shfl_xor(Bv[e], 1 << d);
    }
#pragma unroll
    for (int j = 0; j < 4; ++j)
#pragma unroll
        for (int d = 0; d < 6; ++d) Sq[j] += __shfl_xor(Sq[j], 1 << d);

    if (lane == 0) {
        red[Wp][0] = P;
#pragma unroll
        for (int d = 0; d < 6; ++d) red[Wp][1 + d] = Bv[d];
#pragma unroll
        for (int j = 0; j < 4; ++j) red[Wp][7 + j] = Sq[j];
    }
    __syncthreads();
    if (tid < 16) {
        const int i = tid;  // out index; Z on qubit 15-i
        float r = 0.f;
#pragma unroll
        for (int Wt = 0; Wt < 8; ++Wt) {
            const float Av = red[Wt][0];
            if (i < 4)        r += Av - 2.f * red[Wt][7 + i];    // q15,q14,q13,q12
            else if (i < 10)  r += red[Wt][1 + (i - 4)];         // q11..q6 (lane Walsh)
            else if (i == 10) r += (Wt & 1) ? -Av : Av;          // q5 = Wp b0
            else if (i == 11) r += ((Wt >> 1) & 1) ? -Av : Av;   // q4 = Wp b1
            else              r += Av;                           // q3..q0 block-fixed
        }
        if (i >= 12 && ((J >> (i - 12)) & 1)) r = -r;            // q3..q0 = J b0..b3
        partials[(blk << 4) + i] = r;
    }
}

// ---------------- P2 ----------------
__global__ void qsim_p2(const float* __restrict__ partials, float* __restrict__ out) {
    const int idx = blockIdx.x * 256 + threadIdx.x;  // 2048 outputs
    if (idx < 2048) {
        const int b = idx >> 4, i = idx & 15;
        float s = 0.f;
#pragma unroll
        for (int g = 0; g < 16; ++g) s += partials[(((b << 4) | g) << 4) + i];
        out[idx] = s;
    }
}

extern "C" void kernel_launch(void* const* d_in, const int* in_sizes, int n_in,
                              void* d_out, int out_size, void* d_ws, size_t ws_size,
                              hipStream_t stream) {
    const float* x = (const float*)d_in[0];       // [128,16]
    const float* theta = (const float*)d_in[1];   // [128]
    float* out = (float*)d_out;                   // [128,16]
    float* ws = (float*)d_ws;
    float* st = ws;                               // 8388608 floats = 32 MiB
    float* partials = ws + 8388608;               // 32768 floats used
    float2* tsc = (float2*)(ws + 8388608 + 131072);          // 128 float2
    float4* psit = (float4*)(ws + 8388608 + 131072 + 256);   // 2048 float4

    qsim_pre<<<8, 256, 0, stream>>>(x, theta, tsc, psit);
    qsim_p0<<<512, 1024, 0, stream>>>(psit, tsc, st);
    qsim_p1<<<2048, 512, 0, stream>>>(psit, tsc, st, partials);
    qsim_p2<<<8, 256, 0, stream>>>(partials, out);
}

// Round 7
// 111.542 us; speedup vs baseline: 1.9249x; 1.1772x over previous
//
#include <hip/hip_runtime.h>

// 16-qubit variational-circuit simulator, B=128, re/im split into independent
// real states. Convention (proven): qubit q <-> global flat bit (15-q);
// out[b][i] = <Z_{15-i}> from |amp|^2 signs.
//
// st float layout (proven R3/R5/R6): addr = b<<16 | c<<15 | v(q14)<<14 | l,
//   canonical l (14b): bits13..10 = q0..q3, bits9..6 = q10..q13, bits5..0 = q4..q9.
//
// P0 (512 blk x 1024 thr, 16 reals/thr) — VIEW-SWITCH implementation:
//   Views (regs n / lane / wave w):
//     V1: n=[q0..3], lane=[q4..9] (bit5=q4..bit0=q9), w=[q10..13]  (canonical)
//     V2: n=[q4..7], lane=[bit5..2 = q0..3, bit1=q8, bit0=q9], w=[q10..13]
//     V3: n=[q10..13], lane=[q4..9], w=[q0..3]
//   Trips relabel via 64KB LDS with hash h(l) = l ^ ((l>>8)&0x3C) (bank-conflict-free).
//   Schedule: V1[CZ1,L2:q0-3,8,9] >V2[L2:q4-7] >V3[L2:q10-13,CZ2,L3:q10-12]
//   >V2[L3:4-7] >V1[L3:0-3,8,9,CZ3,L4:0-3,8,9] >V2[L4] >V3[L4:q10,11,CZ4,L5:q10]
//   >V2[L5] >V1[L5,CZ5,L6:0-3,8,9] >V2[L6:4-7,CZ6,L7:4-7] >V1[L7:0-3,8,CZ7,L8:0-3]
//   >V2[L8:4-7,CZ8] >V1 store.   12 trips, 384 DS ops/thread (was 1088).
// P1 (2048 blk x 512 thr, 16 reals/thr) — EXACT R6 proven implementation.

#define DEV __device__ __forceinline__
typedef unsigned long long ull;

DEV float2 cmul(float2 a, float2 b) {
    return make_float2(a.x * b.x - a.y * b.y, a.x * b.y + a.y * b.x);
}

DEV float dpp_xor1(float x) {
    return __int_as_float(__builtin_amdgcn_update_dpp(0, __float_as_int(x), 0xB1, 0xF, 0xF, false));
}
DEV float dpp_xor2(float x) {
    return __int_as_float(__builtin_amdgcn_update_dpp(0, __float_as_int(x), 0x4E, 0xF, 0xF, false));
}

// ---------------- precompute tables ----------------
__global__ void qsim_pre(const float* __restrict__ x, const float* __restrict__ theta,
                         float2* __restrict__ tsc, float4* __restrict__ psit) {
    const int t = blockIdx.x * 256 + threadIdx.x;
    if (t < 128) {
        float S, C; sincosf(0.5f * theta[t], &S, &C);
        tsc[t] = make_float2(C, S);
    }
    if (t < 2048) {
        const int b = t >> 4, q = t & 15;
        float sa, ca, SA, CA;
        sincosf(0.5f * x[b * 16 + q], &sa, &ca);
        sincosf(0.5f * theta[q], &SA, &CA);
        psit[t] = make_float4(CA * ca, SA * sa, SA * ca, -CA * sa);
    }
}

// ---------------- P0 gate helpers ----------------
template <int MB>
DEV void ryb(float (&a)[16], float2 cs) {
    const float C = cs.x, S = cs.y;
#pragma unroll
    for (int n = 0; n < 16; ++n)
        if (!(n & MB)) {
            float t0 = a[n], t1 = a[n | MB];
            a[n]      = C * t0 - S * t1;
            a[n | MB] = S * t0 + C * t1;
        }
}
DEV void ryd1(float (&a)[16], float2 cs, int lane) {  // gate on lane bit0
    const float C = cs.x, Sg = (lane & 1) ? cs.y : -cs.y;
#pragma unroll
    for (int n = 0; n < 16; ++n) { float p = dpp_xor1(a[n]); a[n] = C * a[n] + Sg * p; }
}
DEV void ryd2(float (&a)[16], float2 cs, int lane) {  // gate on lane bit1
    const float C = cs.x, Sg = ((lane >> 1) & 1) ? cs.y : -cs.y;
#pragma unroll
    for (int n = 0; n < 16; ++n) { float p = dpp_xor2(a[n]); a[n] = C * a[n] + Sg * p; }
}
DEV void sgnapply(float (&a)[16], unsigned W) {
#pragma unroll
    for (int n = 0; n < 16; ++n) {
        unsigned sg = ((W >> n) & 1u) << 31;
        a[n] = __uint_as_float(__float_as_uint(a[n]) ^ sg);
    }
}

// CZ amp masks. V3 regs: n3=q10,n2=q11,n1=q12,n0=q13. Pairs (q,q+1) incl. iff q<=14-K.
constexpr unsigned czV3ampK(int K) {
    unsigned m = 0;
    for (int n = 0; n < 16; ++n) {
        int b3 = (n >> 3) & 1, b2 = (n >> 2) & 1, b1 = (n >> 1) & 1, b0 = n & 1;
        int p = 0;
        if (10 <= 14 - K) p ^= b3 & b2;
        if (11 <= 14 - K) p ^= b2 & b1;
        if (12 <= 14 - K) p ^= b1 & b0;
        m |= (unsigned)(p & 1) << n;
    }
    return m;
}
// V2 regs: n3=q4,n2=q5,n1=q6,n0=q7.
constexpr unsigned czV2ampK(int K) {
    unsigned m = 0;
    for (int n = 0; n < 16; ++n) {
        int b3 = (n >> 3) & 1, b2 = (n >> 2) & 1, b1 = (n >> 1) & 1, b0 = n & 1;
        int p = 0;
        if (4 <= 14 - K) p ^= b3 & b2;
        if (5 <= 14 - K) p ^= b2 & b1;
        if (6 <= 14 - K) p ^= b1 & b0;
        m |= (unsigned)(p & 1) << n;
    }
    return m;
}
template <int K>
DEV void czV3(float (&a)[16], int lane, unsigned T3) {
    // used for K=2,4: pair (q9,q10)=l0&n3 included (9<=14-K); (q13,q14) excluded.
    unsigned W = czV3ampK(K);
    if (lane & 1) W ^= 0xFF00u;
    if (T3) W ^= 0xFFFFu;
    sgnapply(a, W);
}
template <int K>
DEV void czV2(float (&a)[16], int lane) {
    // used for K=6 (pairs q<=8) and K=8 (pairs q<=6).
    unsigned W = czV2ampK(K);
    if ((lane >> 2) & 1) W ^= 0xFF00u;                       // (q3,q4) = l2 & n3
    if (K <= 7 && ((lane >> 1) & 1)) W ^= 0xAAAAu;           // (q7,q8) = n0 & l1
    const unsigned LL = (unsigned)(lane & (lane >> 1));      // bit i = l_i & l_{i+1}
    const unsigned msk = (K <= 6) ? 0x1Du : 0x1Cu;           // (q0,q1),(q1,q2),(q2,q3)[,(q8,q9)]
    if (__popc(LL & msk) & 1) sgnapply(a, W ^ 0xFFFFu);
    else sgnapply(a, W);
}

// trip address formulas: h(l) = l ^ ((l>>8)&0x3C), l = canonical 14-bit amp index.
#define IDXV1(n) (bV1i ^ (((n) << 10) | ((n) << 2)))
#define IDXV2(n) (bV2i ^ ((n) << 2))
#define IDXV3(n) (bV3i | ((n) << 6))
#define TRIP(SRC, DST)                                             \
    {                                                              \
        __syncthreads();                                           \
        _Pragma("unroll") for (int n = 0; n < 16; ++n) X[SRC(n)] = a[n]; \
        __syncthreads();                                           \
        _Pragma("unroll") for (int n = 0; n < 16; ++n) a[n] = X[DST(n)]; \
    }

// ---------------- P0 ----------------
__global__ __launch_bounds__(1024, 8) void qsim_p0(const float4* __restrict__ psit,
                                                   const float2* __restrict__ tsc,
                                                   float* __restrict__ st) {
    const int bx = blockIdx.x;
    const int b = bx >> 2, v = (bx >> 1) & 1, c = bx & 1;
    const int tid = threadIdx.x;
    const int lane = tid & 63, w = tid >> 6;

    __shared__ float X[16384];  // 64 KB view-switch buffer

    // ---- product init through RY1 (proven, V1 layout) ----
    const float4* pb = psit + b * 16;
    float2 common = make_float2(1.f, 0.f);
#pragma unroll
    for (int q = 4; q <= 9; ++q) {
        float4 p = pb[q];
        int bit = (lane >> (9 - q)) & 1;
        common = cmul(common, bit ? make_float2(p.z, p.w) : make_float2(p.x, p.y));
    }
#pragma unroll
    for (int q = 10; q <= 13; ++q) {
        float4 p = pb[q];
        int bit = (w >> (13 - q)) & 1;
        common = cmul(common, bit ? make_float2(p.z, p.w) : make_float2(p.x, p.y));
    }
    {
        float4 p = pb[14];
        common = cmul(common, v ? make_float2(p.z, p.w) : make_float2(p.x, p.y));
    }
    float2 ps0[4], ps1[4];
#pragma unroll
    for (int q = 0; q < 4; ++q) {
        float4 p = pb[q];
        ps0[q] = make_float2(p.x, p.y);
        ps1[q] = make_float2(p.z, p.w);
    }

    float a[16];
#pragma unroll
    for (int m = 0; m < 16; ++m) {
        float2 prod = common;
#pragma unroll
        for (int q = 0; q < 4; ++q) {
            int bit = (m >> (3 - q)) & 1;
            prod = cmul(prod, bit ? ps1[q] : ps0[q]);
        }
        a[m] = c ? prod.y : prod.x;
    }

    // ---- CZ V1 machinery (proven) ----
    unsigned Pm = 0;
    const int l5 = (lane >> 5) & 1;  // q4
#pragma unroll
    for (int m = 0; m < 16; ++m) {
        int m0 = m & 1, m1 = (m >> 1) & 1, m2 = (m >> 2) & 1, m3 = (m >> 3) & 1;
        int pm = ((m3 & m2) ^ (m2 & m1) ^ (m1 & m0) ^ (m0 & l5)) & 1;
        Pm |= ((unsigned)pm) << m;
    }
    const unsigned A = ((unsigned)lane << 5) | ((unsigned)w << 1) | (unsigned)v;
    const unsigned AA = (A & (A >> 1)) & 0x3FFu;

    auto czP0 = [&](int k) {
        unsigned T = __popc(AA >> (k - 1)) & 1u;
        unsigned Wm = T ? (Pm ^ 0xFFFFu) : Pm;
        sgnapply(a, Wm);
    };

    // ---- trip bases + V3 thread parity ----
    const int Lhi = lane >> 2, Llo = lane & 3;
    const int bV1i = (w << 6) | lane;
    const int bV2i = (Lhi << 10) | (w << 6) | (Lhi << 2) | Llo;
    const int bV3i = (w << 10) | (lane ^ (w << 2));
    const unsigned B3 = ((unsigned)w << 6) | (unsigned)lane;
    const unsigned T3 = (unsigned)(__popc((B3 & (B3 >> 1)) & 0x1FFu) & 1);

    // ---- schedule ----
    czP0(1);
    // V1: L2 q0..3, q8, q9
    ryb<8>(a, tsc[16 + 0]); ryb<4>(a, tsc[16 + 1]); ryb<2>(a, tsc[16 + 2]); ryb<1>(a, tsc[16 + 3]);
    ryd2(a, tsc[16 + 8], lane); ryd1(a, tsc[16 + 9], lane);
    TRIP(IDXV1, IDXV2);
    // V2: L2 q4..7
    ryb<8>(a, tsc[16 + 4]); ryb<4>(a, tsc[16 + 5]); ryb<2>(a, tsc[16 + 6]); ryb<1>(a, tsc[16 + 7]);
    TRIP(IDXV2, IDXV3);
    // V3: L2 q10..13; CZ2; L3 q10..12
    ryb<8>(a, tsc[16 + 10]); ryb<4>(a, tsc[16 + 11]); ryb<2>(a, tsc[16 + 12]); ryb<1>(a, tsc[16 + 13]);
    czV3<2>(a, lane, T3);
    ryb<8>(a, tsc[32 + 10]); ryb<4>(a, tsc[32 + 11]); ryb<2>(a, tsc[32 + 12]);
    TRIP(IDXV3, IDXV2);
    // V2: L3 q4..7
    ryb<8>(a, tsc[32 + 4]); ryb<4>(a, tsc[32 + 5]); ryb<2>(a, tsc[32 + 6]); ryb<1>(a, tsc[32 + 7]);
    TRIP(IDXV2, IDXV1);
    // V1: L3 q0..3,q8,q9; CZ3; L4 q0..3,q8,q9
    ryb<8>(a, tsc[32 + 0]); ryb<4>(a, tsc[32 + 1]); ryb<2>(a, tsc[32 + 2]); ryb<1>(a, tsc[32 + 3]);
    ryd2(a, tsc[32 + 8], lane); ryd1(a, tsc[32 + 9], lane);
    czP0(3);
    ryb<8>(a, tsc[48 + 0]); ryb<4>(a, tsc[48 + 1]); ryb<2>(a, tsc[48 + 2]); ryb<1>(a, tsc[48 + 3]);
    ryd2(a, tsc[48 + 8], lane); ryd1(a, tsc[48 + 9], lane);
    TRIP(IDXV1, IDXV2);
    // V2: L4 q4..7
    ryb<8>(a, tsc[48 + 4]); ryb<4>(a, tsc[48 + 5]); ryb<2>(a, tsc[48 + 6]); ryb<1>(a, tsc[48 + 7]);
    TRIP(IDXV2, IDXV3);
    // V3: L4 q10,q11; CZ4; L5 q10
    ryb<8>(a, tsc[48 + 10]); ryb<4>(a, tsc[48 + 11]);
    czV3<4>(a, lane, T3);
    ryb<8>(a, tsc[64 + 10]);
    TRIP(IDXV3, IDXV2);
    // V2: L5 q4..7
    ryb<8>(a, tsc[64 + 4]); ryb<4>(a, tsc[64 + 5]); ryb<2>(a, tsc[64 + 6]); ryb<1>(a, tsc[64 + 7]);
    TRIP(IDXV2, IDXV1);
    // V1: L5 q0..3,q8,q9; CZ5; L6 q0..3,q8,q9
    ryb<8>(a, tsc[64 + 0]); ryb<4>(a, tsc[64 + 1]); ryb<2>(a, tsc[64 + 2]); ryb<1>(a, tsc[64 + 3]);
    ryd2(a, tsc[64 + 8], lane); ryd1(a, tsc[64 + 9], lane);
    czP0(5);
    ryb<8>(a, tsc[80 + 0]); ryb<4>(a, tsc[80 + 1]); ryb<2>(a, tsc[80 + 2]); ryb<1>(a, tsc[80 + 3]);
    ryd2(a, tsc[80 + 8], lane); ryd1(a, tsc[80 + 9], lane);
    TRIP(IDXV1, IDXV2);
    // V2: L6 q4..7; CZ6; L7 q4..7
    ryb<8>(a, tsc[80 + 4]); ryb<4>(a, tsc[80 + 5]); ryb<2>(a, tsc[80 + 6]); ryb<1>(a, tsc[80 + 7]);
    czV2<6>(a, lane);
    ryb<8>(a, tsc[96 + 4]); ryb<4>(a, tsc[96 + 5]); ryb<2>(a, tsc[96 + 6]); ryb<1>(a, tsc[96 + 7]);
    TRIP(IDXV2, IDXV1);
    // V1: L7 q0..3,q8; CZ7; L8 q0..3
    ryb<8>(a, tsc[96 + 0]); ryb<4>(a, tsc[96 + 1]); ryb<2>(a, tsc[96 + 2]); ryb<1>(a, tsc[96 + 3]);
    ryd2(a, tsc[96 + 8], lane);
    czP0(7);
    ryb<8>(a, tsc[112 + 0]); ryb<4>(a, tsc[112 + 1]); ryb<2>(a, tsc[112 + 2]); ryb<1>(a, tsc[112 + 3]);
    TRIP(IDXV1, IDXV2);
    // V2: L8 q4..7; CZ8
    ryb<8>(a, tsc[112 + 4]); ryb<4>(a, tsc[112 + 5]); ryb<2>(a, tsc[112 + 6]); ryb<1>(a, tsc[112 + 7]);
    czV2<8>(a, lane);
    TRIP(IDXV2, IDXV1);

    // coalesced store (proven, V1 layout)
    float* outp = st + (((size_t)(b * 2 + c)) << 15) + ((size_t)v << 14);
#pragma unroll
    for (int m = 0; m < 16; ++m) outp[(m << 10) | tid] = a[m];
}

// ---------------- P1 helpers (R6 proven, unchanged) ----------------
template <int K>
constexpr unsigned czmask16() {
    unsigned m = 0;
    for (int n = 0; n < 16; ++n) {
        int n0 = n & 1, n1 = (n >> 1) & 1, n2 = (n >> 2) & 1, n3 = (n >> 3) & 1;
        int p = n1 & n0;
        if (K >= 2) p ^= n2 & n1;
        if (K >= 3) p ^= n3 & n2;
        m |= (unsigned)(p & 1) << n;
    }
    return m;
}

template <int K>
DEV void czp1(float (&a)[16], int lb0, int lb1, int lb2, int lb3) {
    unsigned W = czmask16<K>();
    if (K >= 4 && lb0) W ^= 0xFF00u;
    int T = 0;
    if (K >= 5) T ^= (lb1 & lb0);
    if (K >= 6) T ^= (lb2 & lb1);
    if (K >= 7) T ^= (lb3 & lb2);
    if (T) W ^= 0xFFFFu;
#pragma unroll
    for (int n = 0; n < 16; ++n) {
        unsigned sg = ((W >> n) & 1u) << 31;
        a[n] = __uint_as_float(__float_as_uint(a[n]) ^ sg);
    }
}

template <int MQ>
DEV void rg16(float (&a)[16], float C, float S) {
#pragma unroll
    for (int n = 0; n < 16; ++n)
        if (!(n & MQ)) {
            float t0 = a[n], t1 = a[n | MQ];
            a[n]      = C * t0 - S * t1;
            a[n | MQ] = S * t0 + C * t1;
        }
}

template <int K>
DEV void p1_layer(float (&a)[16], const float2* __restrict__ tsc, int lane) {
    float2 cs = tsc[(K - 1) * 16 + 15]; rg16<1>(a, cs.x, cs.y);
    cs = tsc[(K - 1) * 16 + 14];        rg16<2>(a, cs.x, cs.y);
    if constexpr (K >= 3) { cs = tsc[(K - 1) * 16 + 13]; rg16<4>(a, cs.x, cs.y); }
    if constexpr (K >= 4) { cs = tsc[(K - 1) * 16 + 12]; rg16<8>(a, cs.x, cs.y); }
    if constexpr (K >= 5) {
        cs = tsc[(K - 1) * 16 + 11];
        const float C = cs.x, Sg = (lane & 1) ? cs.y : -cs.y;
#pragma unroll
        for (int n = 0; n < 16; ++n) { float p = dpp_xor1(a[n]); a[n] = C * a[n] + Sg * p; }
    }
    if constexpr (K >= 6) {
        cs = tsc[(K - 1) * 16 + 10];
        const float C = cs.x, Sg = ((lane >> 1) & 1) ? cs.y : -cs.y;
#pragma unroll
        for (int n = 0; n < 16; ++n) { float p = dpp_xor2(a[n]); a[n] = C * a[n] + Sg * p; }
    }
    if constexpr (K >= 7) {
        cs = tsc[(K - 1) * 16 + 9];
        const float C = cs.x, Sg = ((lane >> 2) & 1) ? cs.y : -cs.y;
#pragma unroll
        for (int n = 0; n < 16; ++n) { float p = __shfl_xor(a[n], 4); a[n] = C * a[n] + Sg * p; }
    }
    if constexpr (K >= 8) {
        cs = tsc[(K - 1) * 16 + 8];
        const float C = cs.x, Sg = ((lane >> 3) & 1) ? cs.y : -cs.y;
#pragma unroll
        for (int n = 0; n < 16; ++n) { float p = __shfl_xor(a[n], 8); a[n] = C * a[n] + Sg * p; }
    }
    if constexpr (K < 8) {
        const int lb0 = lane & 1, lb1 = (lane >> 1) & 1, lb2 = (lane >> 2) & 1, lb3 = (lane >> 3) & 1;
        czp1<K>(a, lb0, lb1, lb2, lb3);
    }
}

// ---------------- P1 (R6 proven, unchanged) ----------------
__global__ __launch_bounds__(512, 4) void qsim_p1(const float4* __restrict__ psit,
                                                  const float2* __restrict__ tsc,
                                                  const float* __restrict__ st,
                                                  float* __restrict__ partials) {
    const int blk = blockIdx.x;
    const int b = blk >> 4, J = blk & 15;
    const int tid = threadIdx.x;
    const int lane = tid & 63, Wp = tid >> 6;
    const int c = (Wp >> 2) & 1, q4 = (Wp >> 1) & 1, q5 = Wp & 1;

    __shared__ float red[8][11];

    const float4 p15 = psit[b * 16 + 15];
    const float cB0 = c ? p15.y : -p15.y;
    const float cB1 = c ? p15.w : -p15.w;

    const int laneoff = (((lane >> 1) & 1) << 9) | ((lane & 1) << 8) | ((lane >> 2) & 15);
    const int fixoff = (J << 10) | (q4 << 5) | (q5 << 4) | laneoff;
    const float* pA = st + (((size_t)b) << 16) + ((size_t)c << 15) + fixoff;
    const float* pB = st + (((size_t)b) << 16) + ((size_t)(c ^ 1) << 15) + fixoff;

    float a[16];
#pragma unroll
    for (int q12 = 0; q12 < 2; ++q12)
#pragma unroll
        for (int q13 = 0; q13 < 2; ++q13)
#pragma unroll
            for (int q14 = 0; q14 < 2; ++q14) {
                const int off = (q14 << 14) | (q12 << 7) | (q13 << 6);
                const float rA = pA[off], rB = pB[off];
                const int n = (q12 << 3) | (q13 << 2) | (q14 << 1);
                a[n]     = p15.x * rA + cB0 * rB;
                a[n | 1] = p15.z * rA + cB1 * rB;
            }

    {
        const int lb0 = lane & 1, lb1 = (lane >> 1) & 1, lb2 = (lane >> 2) & 1, lb3 = (lane >> 3) & 1;
        czp1<1>(a, lb0, lb1, lb2, lb3);
    }
    p1_layer<2>(a, tsc, lane);
    p1_layer<3>(a, tsc, lane);
    p1_layer<4>(a, tsc, lane);
    p1_layer<5>(a, tsc, lane);
    p1_layer<6>(a, tsc, lane);
    p1_layer<7>(a, tsc, lane);
    p1_layer<8>(a, tsc, lane);

    float Ssum = 0.f, Sq[4] = {0.f, 0.f, 0.f, 0.f};
#pragma unroll
    for (int n = 0; n < 16; ++n) {
        float pm = a[n] * a[n];
        Ssum += pm;
        if (n & 1) Sq[0] += pm;
        if (n & 2) Sq[1] += pm;
        if (n & 4) Sq[2] += pm;
        if (n & 8) Sq[3] += pm;
    }
    float P = Ssum, Bv[6];
#pragma unroll
    for (int d = 0; d < 6; ++d) {
        float t = __shfl_xor(P, 1 << d);
        Bv[d] = ((lane >> d) & 1) ? (t - P) : (P - t);
        P += t;
#pragma unroll
        for (int e = 0; e < 6; ++e)
            if (e < d) Bv[e] += __shfl_xor(Bv[e], 1 << d);
    }
#pragma unroll
    for (int j = 0; j < 4; ++j)
#pragma unroll
        for (int d = 0; d < 6; ++d) Sq[j] += __shfl_xor(Sq[j], 1 << d);

    if (lane == 0) {
        red[Wp][0] = P;
#pragma unroll
        for (int d = 0; d < 6; ++d) red[Wp][1 + d] = Bv[d];
#pragma unroll
        for (int j = 0; j < 4; ++j) red[Wp][7 + j] = Sq[j];
    }
    __syncthreads();
    if (tid < 16) {
        const int i = tid;
        float r = 0.f;
#pragma unroll
        for (int Wt = 0; Wt < 8; ++Wt) {
            const float Av = red[Wt][0];
            if (i < 4)        r += Av - 2.f * red[Wt][7 + i];
            else if (i < 10)  r += red[Wt][1 + (i - 4)];
            else if (i == 10) r += (Wt & 1) ? -Av : Av;
            else if (i == 11) r += ((Wt >> 1) & 1) ? -Av : Av;
            else              r += Av;
        }
        if (i >= 12 && ((J >> (i - 12)) & 1)) r = -r;
        partials[(blk << 4) + i] = r;
    }
}

// ---------------- P2 ----------------
__global__ void qsim_p2(const float* __restrict__ partials, float* __restrict__ out) {
    const int idx = blockIdx.x * 256 + threadIdx.x;
    if (idx < 2048) {
        const int b = idx >> 4, i = idx & 15;
        float s = 0.f;
#pragma unroll
        for (int g = 0; g < 16; ++g) s += partials[(((b << 4) | g) << 4) + i];
        out[idx] = s;
    }
}

extern "C" void kernel_launch(void* const* d_in, const int* in_sizes, int n_in,
                              void* d_out, int out_size, void* d_ws, size_t ws_size,
                              hipStream_t stream) {
    const float* x = (const float*)d_in[0];       // [128,16]
    const float* theta = (const float*)d_in[1];   // [128]
    float* out = (float*)d_out;                   // [128,16]
    float* ws = (float*)d_ws;
    float* st = ws;                               // 8388608 floats = 32 MiB
    float* partials = ws + 8388608;               // 32768 floats used
    float2* tsc = (float2*)(ws + 8388608 + 131072);          // 128 float2
    float4* psit = (float4*)(ws + 8388608 + 131072 + 256);   // 2048 float4

    qsim_pre<<<8, 256, 0, stream>>>(x, theta, tsc, psit);
    qsim_p0<<<512, 1024, 0, stream>>>(psit, tsc, st);
    qsim_p1<<<2048, 512, 0, stream>>>(psit, tsc, st, partials);
    qsim_p2<<<8, 256, 0, stream>>>(partials, out);
}

// Round 8
// 95.104 us; speedup vs baseline: 2.2576x; 1.1728x over previous
//
#include <hip/hip_runtime.h>

// 16-qubit variational-circuit simulator, B=128, re/im split into independent
// real states, amplitudes held as PACKED float2 (v_pk_fma_f32 path).
// Convention (proven): qubit q <-> global flat bit (15-q); out[b][i] = <Z_{15-i}>.
//
// st float layout (proven): addr = b<<16 | c<<15 | v(q14)<<14 | l,
//   canonical l (14b): bits13..10 = q0..q3, bits9..6 = q10..q13, bits5..0 = q4..q9.
//
// P0 (512 blk x 1024 thr, 16 reals/thr as pk2 A[8]) — R7 view-switch schedule:
//   V1: n=[q0..3], lane=[q4..9], w=[q10..13]; V2: n=[q4..7]; V3: n=[q10..13].
//   12 LDS trips, hash h(l) = l ^ ((l>>8)&0x3C), bank-conflict-free (proven R7).
//   Amp index n = (j<<1)|e, e = element of pk2; n bit0 gate = horizontal (.yx).
// P1 (2048 blk x 512 thr) — R6 proven mapping, packed arithmetic.

#define DEV __device__ __forceinline__
typedef unsigned long long ull;
typedef __attribute__((ext_vector_type(2))) float pk2;

DEV pk2 sp2(float v) { return (pk2){v, v}; }

DEV float2 cmul(float2 a, float2 b) {
    return make_float2(a.x * b.x - a.y * b.y, a.x * b.y + a.y * b.x);
}

DEV float dpp_xor1(float x) {
    return __int_as_float(__builtin_amdgcn_update_dpp(0, __float_as_int(x), 0xB1, 0xF, 0xF, false));
}
DEV float dpp_xor2(float x) {
    return __int_as_float(__builtin_amdgcn_update_dpp(0, __float_as_int(x), 0x4E, 0xF, 0xF, false));
}

// ---------------- packed gate helpers ----------------
template <int MJ>
DEV void ry_v(pk2 (&A)[8], float2 cs) {   // pair bit MJ in j-space (n bit = 2*MJ)
    const float C = cs.x, S = cs.y;
#pragma unroll
    for (int j = 0; j < 8; ++j)
        if (!(j & MJ)) {
            pk2 t0 = A[j], t1 = A[j | MJ];
            A[j]      = t0 * sp2(C) - t1 * sp2(S);
            A[j | MJ] = t0 * sp2(S) + t1 * sp2(C);
        }
}
DEV void ry_h(pk2 (&A)[8], float2 cs) {   // pair = n bit0 (element bit)
    const float C = cs.x, S = cs.y;
    const pk2 SN = (pk2){-S, S};
#pragma unroll
    for (int j = 0; j < 8; ++j) {
        pk2 t = A[j];
        A[j] = t * sp2(C) + t.yx * SN;
    }
}
DEV void ry_d1(pk2 (&A)[8], float2 cs, int lane) {  // gate on lane bit0
    const float C = cs.x, Sg = (lane & 1) ? cs.y : -cs.y;
#pragma unroll
    for (int j = 0; j < 8; ++j) {
        pk2 p; p.x = dpp_xor1(A[j].x); p.y = dpp_xor1(A[j].y);
        A[j] = A[j] * sp2(C) + p * sp2(Sg);
    }
}
DEV void ry_d2(pk2 (&A)[8], float2 cs, int lane) {  // gate on lane bit1
    const float C = cs.x, Sg = ((lane >> 1) & 1) ? cs.y : -cs.y;
#pragma unroll
    for (int j = 0; j < 8; ++j) {
        pk2 p; p.x = dpp_xor2(A[j].x); p.y = dpp_xor2(A[j].y);
        A[j] = A[j] * sp2(C) + p * sp2(Sg);
    }
}
DEV void ry_sh(pk2 (&A)[8], float2 cs, int lane, int lb) {  // gate on lane bit lb (shfl)
    const float C = cs.x, Sg = ((lane >> lb) & 1) ? cs.y : -cs.y;
#pragma unroll
    for (int j = 0; j < 8; ++j) {
        pk2 p; p.x = __shfl_xor(A[j].x, 1 << lb); p.y = __shfl_xor(A[j].y, 1 << lb);
        A[j] = A[j] * sp2(C) + p * sp2(Sg);
    }
}
DEV void sgnapply2(pk2 (&A)[8], unsigned W) {  // W over n = (j<<1)|e
#pragma unroll
    for (int j = 0; j < 8; ++j) {
        unsigned sx = ((W >> (2 * j)) & 1u) << 31;
        unsigned sy = ((W >> (2 * j + 1)) & 1u) << 31;
        A[j].x = __uint_as_float(__float_as_uint(A[j].x) ^ sx);
        A[j].y = __uint_as_float(__float_as_uint(A[j].y) ^ sy);
    }
}

// ---------------- precompute tables ----------------
__global__ void qsim_pre(const float* __restrict__ x, const float* __restrict__ theta,
                         float2* __restrict__ tsc, float4* __restrict__ psit) {
    const int t = blockIdx.x * 256 + threadIdx.x;
    if (t < 128) {
        float S, C; sincosf(0.5f * theta[t], &S, &C);
        tsc[t] = make_float2(C, S);
    }
    if (t < 2048) {
        const int b = t >> 4, q = t & 15;
        float sa, ca, SA, CA;
        sincosf(0.5f * x[b * 16 + q], &sa, &ca);
        sincosf(0.5f * theta[q], &SA, &CA);
        psit[t] = make_float4(CA * ca, SA * sa, SA * ca, -CA * sa);
    }
}

// CZ amp masks (proven R7). V3 regs: n3=q10..n0=q13; V2 regs: n3=q4..n0=q7.
constexpr unsigned czV3ampK(int K) {
    unsigned m = 0;
    for (int n = 0; n < 16; ++n) {
        int b3 = (n >> 3) & 1, b2 = (n >> 2) & 1, b1 = (n >> 1) & 1, b0 = n & 1;
        int p = 0;
        if (10 <= 14 - K) p ^= b3 & b2;
        if (11 <= 14 - K) p ^= b2 & b1;
        if (12 <= 14 - K) p ^= b1 & b0;
        m |= (unsigned)(p & 1) << n;
    }
    return m;
}
constexpr unsigned czV2ampK(int K) {
    unsigned m = 0;
    for (int n = 0; n < 16; ++n) {
        int b3 = (n >> 3) & 1, b2 = (n >> 2) & 1, b1 = (n >> 1) & 1, b0 = n & 1;
        int p = 0;
        if (4 <= 14 - K) p ^= b3 & b2;
        if (5 <= 14 - K) p ^= b2 & b1;
        if (6 <= 14 - K) p ^= b1 & b0;
        m |= (unsigned)(p & 1) << n;
    }
    return m;
}
template <int K>
DEV void czV3(pk2 (&A)[8], int lane, unsigned T3) {
    unsigned W = czV3ampK(K);
    if (lane & 1) W ^= 0xFF00u;
    if (T3) W ^= 0xFFFFu;
    sgnapply2(A, W);
}
template <int K>
DEV void czV2(pk2 (&A)[8], int lane) {
    unsigned W = czV2ampK(K);
    if ((lane >> 2) & 1) W ^= 0xFF00u;
    if (K <= 7 && ((lane >> 1) & 1)) W ^= 0xAAAAu;
    const unsigned LL = (unsigned)(lane & (lane >> 1));
    const unsigned msk = (K <= 6) ? 0x1Du : 0x1Cu;
    if (__popc(LL & msk) & 1) sgnapply2(A, W ^ 0xFFFFu);
    else sgnapply2(A, W);
}

// trip address formulas (proven R7): h(l) = l ^ ((l>>8)&0x3C)
#define IDXV1(n) (bV1i ^ (((n) << 10) | ((n) << 2)))
#define IDXV2(n) (bV2i ^ ((n) << 2))
#define IDXV3(n) (bV3i | ((n) << 6))
#define TRIP(SRC, DST)                                                       \
    {                                                                        \
        __syncthreads();                                                     \
        _Pragma("unroll") for (int j = 0; j < 8; ++j) {                      \
            X[SRC(2 * j)] = A[j].x; X[SRC(2 * j + 1)] = A[j].y;              \
        }                                                                    \
        __syncthreads();                                                     \
        _Pragma("unroll") for (int j = 0; j < 8; ++j) {                      \
            A[j].x = X[DST(2 * j)]; A[j].y = X[DST(2 * j + 1)];              \
        }                                                                    \
    }

// ---------------- P0 ----------------
__global__ __launch_bounds__(1024, 8) void qsim_p0(const float4* __restrict__ psit,
                                                   const float2* __restrict__ tsc,
                                                   float* __restrict__ st) {
    const int bx = blockIdx.x;
    const int b = bx >> 2, v = (bx >> 1) & 1, c = bx & 1;
    const int tid = threadIdx.x;
    const int lane = tid & 63, w = tid >> 6;

    __shared__ float X[16384];  // 64 KB view-switch buffer

    // ---- product init through RY1 (proven, V1 layout) ----
    const float4* pb = psit + b * 16;
    float2 common = make_float2(1.f, 0.f);
#pragma unroll
    for (int q = 4; q <= 9; ++q) {
        float4 p = pb[q];
        int bit = (lane >> (9 - q)) & 1;
        common = cmul(common, bit ? make_float2(p.z, p.w) : make_float2(p.x, p.y));
    }
#pragma unroll
    for (int q = 10; q <= 13; ++q) {
        float4 p = pb[q];
        int bit = (w >> (13 - q)) & 1;
        common = cmul(common, bit ? make_float2(p.z, p.w) : make_float2(p.x, p.y));
    }
    {
        float4 p = pb[14];
        common = cmul(common, v ? make_float2(p.z, p.w) : make_float2(p.x, p.y));
    }
    float2 ps0[4], ps1[4];
#pragma unroll
    for (int q = 0; q < 4; ++q) {
        float4 p = pb[q];
        ps0[q] = make_float2(p.x, p.y);
        ps1[q] = make_float2(p.z, p.w);
    }

    pk2 A[8];
#pragma unroll
    for (int m = 0; m < 16; ++m) {
        float2 prod = common;
#pragma unroll
        for (int q = 0; q < 4; ++q) {
            int bit = (m >> (3 - q)) & 1;
            prod = cmul(prod, bit ? ps1[q] : ps0[q]);
        }
        float val = c ? prod.y : prod.x;
        if (m & 1) A[m >> 1].y = val; else A[m >> 1].x = val;
    }

    // ---- CZ V1 machinery (proven) ----
    unsigned Pm = 0;
    const int l5 = (lane >> 5) & 1;  // q4
#pragma unroll
    for (int m = 0; m < 16; ++m) {
        int m0 = m & 1, m1 = (m >> 1) & 1, m2 = (m >> 2) & 1, m3 = (m >> 3) & 1;
        int pm = ((m3 & m2) ^ (m2 & m1) ^ (m1 & m0) ^ (m0 & l5)) & 1;
        Pm |= ((unsigned)pm) << m;
    }
    const unsigned Ax = ((unsigned)lane << 5) | ((unsigned)w << 1) | (unsigned)v;
    const unsigned AA = (Ax & (Ax >> 1)) & 0x3FFu;

    auto czP0 = [&](int k) {
        unsigned T = __popc(AA >> (k - 1)) & 1u;
        unsigned Wm = T ? (Pm ^ 0xFFFFu) : Pm;
        sgnapply2(A, Wm);
    };

    // ---- trip bases + V3 thread parity (proven R7) ----
    const int Lhi = lane >> 2, Llo = lane & 3;
    const int bV1i = (w << 6) | lane;
    const int bV2i = (Lhi << 10) | (w << 6) | (Lhi << 2) | Llo;
    const int bV3i = (w << 10) | (lane ^ (w << 2));
    const unsigned B3 = ((unsigned)w << 6) | (unsigned)lane;
    const unsigned T3 = (unsigned)(__popc((B3 & (B3 >> 1)) & 0x1FFu) & 1);

    // ---- schedule (proven R7, packed helpers) ----
    czP0(1);
    // V1: L2 q0..3, q8, q9
    ry_v<4>(A, tsc[16 + 0]); ry_v<2>(A, tsc[16 + 1]); ry_v<1>(A, tsc[16 + 2]); ry_h(A, tsc[16 + 3]);
    ry_d2(A, tsc[16 + 8], lane); ry_d1(A, tsc[16 + 9], lane);
    TRIP(IDXV1, IDXV2);
    // V2: L2 q4..7
    ry_v<4>(A, tsc[16 + 4]); ry_v<2>(A, tsc[16 + 5]); ry_v<1>(A, tsc[16 + 6]); ry_h(A, tsc[16 + 7]);
    TRIP(IDXV2, IDXV3);
    // V3: L2 q10..13; CZ2; L3 q10..12
    ry_v<4>(A, tsc[16 + 10]); ry_v<2>(A, tsc[16 + 11]); ry_v<1>(A, tsc[16 + 12]); ry_h(A, tsc[16 + 13]);
    czV3<2>(A, lane, T3);
    ry_v<4>(A, tsc[32 + 10]); ry_v<2>(A, tsc[32 + 11]); ry_v<1>(A, tsc[32 + 12]);
    TRIP(IDXV3, IDXV2);
    // V2: L3 q4..7
    ry_v<4>(A, tsc[32 + 4]); ry_v<2>(A, tsc[32 + 5]); ry_v<1>(A, tsc[32 + 6]); ry_h(A, tsc[32 + 7]);
    TRIP(IDXV2, IDXV1);
    // V1: L3 q0..3,q8,q9; CZ3; L4 q0..3,q8,q9
    ry_v<4>(A, tsc[32 + 0]); ry_v<2>(A, tsc[32 + 1]); ry_v<1>(A, tsc[32 + 2]); ry_h(A, tsc[32 + 3]);
    ry_d2(A, tsc[32 + 8], lane); ry_d1(A, tsc[32 + 9], lane);
    czP0(3);
    ry_v<4>(A, tsc[48 + 0]); ry_v<2>(A, tsc[48 + 1]); ry_v<1>(A, tsc[48 + 2]); ry_h(A, tsc[48 + 3]);
    ry_d2(A, tsc[48 + 8], lane); ry_d1(A, tsc[48 + 9], lane);
    TRIP(IDXV1, IDXV2);
    // V2: L4 q4..7
    ry_v<4>(A, tsc[48 + 4]); ry_v<2>(A, tsc[48 + 5]); ry_v<1>(A, tsc[48 + 6]); ry_h(A, tsc[48 + 7]);
    TRIP(IDXV2, IDXV3);
    // V3: L4 q10,q11; CZ4; L5 q10
    ry_v<4>(A, tsc[48 + 10]); ry_v<2>(A, tsc[48 + 11]);
    czV3<4>(A, lane, T3);
    ry_v<4>(A, tsc[64 + 10]);
    TRIP(IDXV3, IDXV2);
    // V2: L5 q4..7
    ry_v<4>(A, tsc[64 + 4]); ry_v<2>(A, tsc[64 + 5]); ry_v<1>(A, tsc[64 + 6]); ry_h(A, tsc[64 + 7]);
    TRIP(IDXV2, IDXV1);
    // V1: L5 q0..3,q8,q9; CZ5; L6 q0..3,q8,q9
    ry_v<4>(A, tsc[64 + 0]); ry_v<2>(A, tsc[64 + 1]); ry_v<1>(A, tsc[64 + 2]); ry_h(A, tsc[64 + 3]);
    ry_d2(A, tsc[64 + 8], lane); ry_d1(A, tsc[64 + 9], lane);
    czP0(5);
    ry_v<4>(A, tsc[80 + 0]); ry_v<2>(A, tsc[80 + 1]); ry_v<1>(A, tsc[80 + 2]); ry_h(A, tsc[80 + 3]);
    ry_d2(A, tsc[80 + 8], lane); ry_d1(A, tsc[80 + 9], lane);
    TRIP(IDXV1, IDXV2);
    // V2: L6 q4..7; CZ6; L7 q4..7
    ry_v<4>(A, tsc[80 + 4]); ry_v<2>(A, tsc[80 + 5]); ry_v<1>(A, tsc[80 + 6]); ry_h(A, tsc[80 + 7]);
    czV2<6>(A, lane);
    ry_v<4>(A, tsc[96 + 4]); ry_v<2>(A, tsc[96 + 5]); ry_v<1>(A, tsc[96 + 6]); ry_h(A, tsc[96 + 7]);
    TRIP(IDXV2, IDXV1);
    // V1: L7 q0..3,q8; CZ7; L8 q0..3
    ry_v<4>(A, tsc[96 + 0]); ry_v<2>(A, tsc[96 + 1]); ry_v<1>(A, tsc[96 + 2]); ry_h(A, tsc[96 + 3]);
    ry_d2(A, tsc[96 + 8], lane);
    czP0(7);
    ry_v<4>(A, tsc[112 + 0]); ry_v<2>(A, tsc[112 + 1]); ry_v<1>(A, tsc[112 + 2]); ry_h(A, tsc[112 + 3]);
    TRIP(IDXV1, IDXV2);
    // V2: L8 q4..7; CZ8
    ry_v<4>(A, tsc[112 + 4]); ry_v<2>(A, tsc[112 + 5]); ry_v<1>(A, tsc[112 + 6]); ry_h(A, tsc[112 + 7]);
    czV2<8>(A, lane);
    TRIP(IDXV2, IDXV1);

    // coalesced store (proven, V1 layout)
    float* outp = st + (((size_t)(b * 2 + c)) << 15) + ((size_t)v << 14);
#pragma unroll
    for (int j = 0; j < 8; ++j) {
        outp[((2 * j) << 10) | tid] = A[j].x;
        outp[((2 * j + 1) << 10) | tid] = A[j].y;
    }
}

// ---------------- P1 helpers (R6 proven logic, packed) ----------------
template <int K>
constexpr unsigned czmask16() {
    unsigned m = 0;
    for (int n = 0; n < 16; ++n) {
        int n0 = n & 1, n1 = (n >> 1) & 1, n2 = (n >> 2) & 1, n3 = (n >> 3) & 1;
        int p = n1 & n0;
        if (K >= 2) p ^= n2 & n1;
        if (K >= 3) p ^= n3 & n2;
        m |= (unsigned)(p & 1) << n;
    }
    return m;
}

template <int K>
DEV void czp1(pk2 (&A)[8], int lb0, int lb1, int lb2, int lb3) {
    unsigned W = czmask16<K>();
    if (K >= 4 && lb0) W ^= 0xFF00u;
    int T = 0;
    if (K >= 5) T ^= (lb1 & lb0);
    if (K >= 6) T ^= (lb2 & lb1);
    if (K >= 7) T ^= (lb3 & lb2);
    if (T) W ^= 0xFFFFu;
    sgnapply2(A, W);
}

template <int K>
DEV void p1_layer(pk2 (&A)[8], const float2* __restrict__ tsc, int lane) {
    ry_h(A, tsc[(K - 1) * 16 + 15]);          // q15 (n bit0)
    ry_v<1>(A, tsc[(K - 1) * 16 + 14]);       // q14
    if constexpr (K >= 3) ry_v<2>(A, tsc[(K - 1) * 16 + 13]);
    if constexpr (K >= 4) ry_v<4>(A, tsc[(K - 1) * 16 + 12]);
    if constexpr (K >= 5) ry_d1(A, tsc[(K - 1) * 16 + 11], lane);
    if constexpr (K >= 6) ry_d2(A, tsc[(K - 1) * 16 + 10], lane);
    if constexpr (K >= 7) ry_sh(A, tsc[(K - 1) * 16 + 9], lane, 2);
    if constexpr (K >= 8) ry_sh(A, tsc[(K - 1) * 16 + 8], lane, 3);
    if constexpr (K < 8) {
        const int lb0 = lane & 1, lb1 = (lane >> 1) & 1, lb2 = (lane >> 2) & 1, lb3 = (lane >> 3) & 1;
        czp1<K>(A, lb0, lb1, lb2, lb3);
    }
}

// ---------------- P1 ----------------
__global__ __launch_bounds__(512, 4) void qsim_p1(const float4* __restrict__ psit,
                                                  const float2* __restrict__ tsc,
                                                  const float* __restrict__ st,
                                                  float* __restrict__ partials) {
    const int blk = blockIdx.x;
    const int b = blk >> 4, J = blk & 15;
    const int tid = threadIdx.x;
    const int lane = tid & 63, Wp = tid >> 6;
    const int c = (Wp >> 2) & 1, q4 = (Wp >> 1) & 1, q5 = Wp & 1;

    __shared__ float red[8][11];

    const float4 p15 = psit[b * 16 + 15];
    const float cB0 = c ? p15.y : -p15.y;
    const float cB1 = c ? p15.w : -p15.w;
    const pk2 P0pk = (pk2){p15.x, p15.z};
    const pk2 CBpk = (pk2){cB0, cB1};

    const int laneoff = (((lane >> 1) & 1) << 9) | ((lane & 1) << 8) | ((lane >> 2) & 15);
    const int fixoff = (J << 10) | (q4 << 5) | (q5 << 4) | laneoff;
    const float* pA = st + (((size_t)b) << 16) + ((size_t)c << 15) + fixoff;
    const float* pB = st + (((size_t)b) << 16) + ((size_t)(c ^ 1) << 15) + fixoff;

    pk2 A[8];  // n = (j<<1)|e: e=q15, j b0=q14, j b1=q13, j b2=q12
#pragma unroll
    for (int q12 = 0; q12 < 2; ++q12)
#pragma unroll
        for (int q13 = 0; q13 < 2; ++q13)
#pragma unroll
            for (int q14 = 0; q14 < 2; ++q14) {
                const int off = (q14 << 14) | (q12 << 7) | (q13 << 6);
                const float rA = pA[off], rB = pB[off];
                const int j = (q12 << 2) | (q13 << 1) | q14;
                A[j] = P0pk * sp2(rA) + CBpk * sp2(rB);
            }

    {
        const int lb0 = lane & 1, lb1 = (lane >> 1) & 1, lb2 = (lane >> 2) & 1, lb3 = (lane >> 3) & 1;
        czp1<1>(A, lb0, lb1, lb2, lb3);
    }
    p1_layer<2>(A, tsc, lane);
    p1_layer<3>(A, tsc, lane);
    p1_layer<4>(A, tsc, lane);
    p1_layer<5>(A, tsc, lane);
    p1_layer<6>(A, tsc, lane);
    p1_layer<7>(A, tsc, lane);
    p1_layer<8>(A, tsc, lane);

    // ---- measurement ----
    float Ssum = 0.f, Sq[4] = {0.f, 0.f, 0.f, 0.f};
#pragma unroll
    for (int j = 0; j < 8; ++j) {
        pk2 pv = A[j] * A[j];
        float both = pv.x + pv.y;
        Ssum += both;
        Sq[0] += pv.y;            // n bit0 = q15
        if (j & 1) Sq[1] += both; // n bit1 = q14
        if (j & 2) Sq[2] += both; // q13
        if (j & 4) Sq[3] += both; // q12
    }
    float P = Ssum, Bv[6];
#pragma unroll
    for (int d = 0; d < 6; ++d) {
        float t = __shfl_xor(P, 1 << d);
        Bv[d] = ((lane >> d) & 1) ? (t - P) : (P - t);
        P += t;
#pragma unroll
        for (int e = 0; e < 6; ++e)
            if (e < d) Bv[e] += __shfl_xor(Bv[e], 1 << d);
    }
#pragma unroll
    for (int j = 0; j < 4; ++j)
#pragma unroll
        for (int d = 0; d < 6; ++d) Sq[j] += __shfl_xor(Sq[j], 1 << d);

    if (lane == 0) {
        red[Wp][0] = P;
#pragma unroll
        for (int d = 0; d < 6; ++d) red[Wp][1 + d] = Bv[d];
#pragma unroll
        for (int j = 0; j < 4; ++j) red[Wp][7 + j] = Sq[j];
    }
    __syncthreads();
    if (tid < 16) {
        const int i = tid;
        float r = 0.f;
#pragma unroll
        for (int Wt = 0; Wt < 8; ++Wt) {
            const float Av = red[Wt][0];
            if (i < 4)        r += Av - 2.f * red[Wt][7 + i];
            else if (i < 10)  r += red[Wt][1 + (i - 4)];
            else if (i == 10) r += (Wt & 1) ? -Av : Av;
            else if (i == 11) r += ((Wt >> 1) & 1) ? -Av : Av;
            else              r += Av;
        }
        if (i >= 12 && ((J >> (i - 12)) & 1)) r = -r;
        partials[(blk << 4) + i] = r;
    }
}

// ---------------- P2 ----------------
__global__ void qsim_p2(const float* __restrict__ partials, float* __restrict__ out) {
    const int idx = blockIdx.x * 256 + threadIdx.x;
    if (idx < 2048) {
        const int b = idx >> 4, i = idx & 15;
        float s = 0.f;
#pragma unroll
        for (int g = 0; g < 16; ++g) s += partials[(((b << 4) | g) << 4) + i];
        out[idx] = s;
    }
}

extern "C" void kernel_launch(void* const* d_in, const int* in_sizes, int n_in,
                              void* d_out, int out_size, void* d_ws, size_t ws_size,
                              hipStream_t stream) {
    const float* x = (const float*)d_in[0];       // [128,16]
    const float* theta = (const float*)d_in[1];   // [128]
    float* out = (float*)d_out;                   // [128,16]
    float* ws = (float*)d_ws;
    float* st = ws;                               // 8388608 floats = 32 MiB
    float* partials = ws + 8388608;               // 32768 floats used
    float2* tsc = (float2*)(ws + 8388608 + 131072);          // 128 float2
    float4* psit = (float4*)(ws + 8388608 + 131072 + 256);   // 2048 float4

    qsim_pre<<<8, 256, 0, stream>>>(x, theta, tsc, psit);
    qsim_p0<<<512, 1024, 0, stream>>>(psit, tsc, st);
    qsim_p1<<<2048, 512, 0, stream>>>(psit, tsc, st, partials);
    qsim_p2<<<8, 256, 0, stream>>>(partials, out);
}